// Round 10
// baseline (440.908 us; speedup 1.0000x reference)
//
#include <hip/hip_runtime.h>
#include <hip/hip_bf16.h>

#define NN 20000
#define NE 320000
#define ET 340000            // NE + NN self loops
#define NEG_SLOPE 0.2f

typedef __attribute__((ext_vector_type(8))) _Float16 f16x8;
typedef __attribute__((ext_vector_type(4))) _Float16 f16x4;
typedef __attribute__((ext_vector_type(4))) float f32x4;

typedef __attribute__((address_space(3))) unsigned int lds_u32_t;
typedef __attribute__((address_space(1))) unsigned int glb_u32_t;

__device__ __forceinline__ void gload_lds16(const void* g, void* l) {
  __builtin_amdgcn_global_load_lds((const glb_u32_t*)g, (lds_u32_t*)l, 16, 0, 0);
}

// ---- fused init: 3 weight transposes + zero cnt + zero als/ald + x->f16 ----
// blocks [0,1312): tiled transposes Wt[n][k] = (f16)W[k][n]
//   W1 768x1024 -> 768 blocks; W2 1024x512 -> 512; W3 512x64 -> 32.
// blocks [1312,...): grid-stride init work.
__global__ __launch_bounds__(256) void k_init(
    const float* __restrict__ x, _Float16* __restrict__ xb,
    int* __restrict__ cnt, float* __restrict__ zb, int nz,
    const float* __restrict__ W1, _Float16* __restrict__ Wt1,
    const float* __restrict__ W2, _Float16* __restrict__ Wt2,
    const float* __restrict__ W3, _Float16* __restrict__ Wt3) {
  __shared__ float tile[32][33];
  if (blockIdx.x < 1312) {
    int b = blockIdx.x;
    const float* W; _Float16* Wt; int K, N, bk, bn;
    if (b < 768)       { W = W1; Wt = Wt1; K = 768;  N = 1024; bn = (b % 32) * 32; bk = (b / 32) * 32; }
    else if (b < 1280) { b -= 768;  W = W2; Wt = Wt2; K = 1024; N = 512; bn = (b % 16) * 32; bk = (b / 16) * 32; }
    else               { b -= 1280; W = W3; Wt = Wt3; K = 512;  N = 64;  bn = (b % 2) * 32;  bk = (b / 2) * 32; }
    int tx = threadIdx.x & 31, ty = threadIdx.x >> 5;  // 32 x 8
#pragma unroll
    for (int r = ty; r < 32; r += 8)
      tile[r][tx] = W[(size_t)(bk + r) * N + bn + tx];
    __syncthreads();
#pragma unroll
    for (int r = ty; r < 32; r += 8)
      Wt[(size_t)(bn + r) * K + bk + tx] = (_Float16)tile[tx][r];
    return;
  }
  const int stride = (gridDim.x - 1312) * blockDim.x;
  const int i0 = (blockIdx.x - 1312) * blockDim.x + threadIdx.x;
  for (int i = i0; i < NN; i += stride) cnt[i] = 0;
  for (int i = i0; i < nz; i += stride) zb[i] = 0.f;
  const int n4 = NN * 768 / 4;
  for (int i = i0; i < n4; i += stride) {
    f32x4 v = *(const f32x4*)&x[i * 4];
    f16x4 h = { (_Float16)v.x, (_Float16)v.y, (_Float16)v.z, (_Float16)v.w };
    *(f16x4*)&xb[i * 4] = h;
  }
}

// ---------------- CSR build -------------------------------------------------
__global__ void k_count(const int* __restrict__ ei, int* __restrict__ cnt) {
  int e = blockIdx.x * blockDim.x + threadIdx.x;
  if (e >= ET) return;
  int d = (e < NE) ? ei[NE + e] : (e - NE);
  atomicAdd(&cnt[d], 1);
}

// one-pass single-block scan: 1024 threads x 20 elements each
__global__ __launch_bounds__(1024) void k_scan(const int* __restrict__ cnt,
                                               int* __restrict__ rptr,
                                               int* __restrict__ cursor) {
  const int CH = 20;  // 1024*20 = 20480 >= NN
  int t = threadIdx.x, lane = t & 63, wid = t >> 6;
  int base = t * CH;
  int v[CH];
  int sum = 0;
#pragma unroll
  for (int j = 0; j < CH; ++j) {
    int idx = base + j;
    v[j] = (idx < NN) ? cnt[idx] : 0;
    sum += v[j];
  }
  int ws = sum;  // inclusive wave scan
#pragma unroll
  for (int off = 1; off < 64; off <<= 1) {
    int u = __shfl_up(ws, off);
    if (lane >= off) ws += u;
  }
  __shared__ int wsum[16];
  __shared__ int wpre[16];
  if (lane == 63) wsum[wid] = ws;
  __syncthreads();
  if (t == 0) {
    int acc = 0;
#pragma unroll
    for (int w = 0; w < 16; ++w) { wpre[w] = acc; acc += wsum[w]; }
  }
  __syncthreads();
  int run = wpre[wid] + ws - sum;  // exclusive prefix of this chunk
  if (t == 0) rptr[0] = 0;
#pragma unroll
  for (int j = 0; j < CH; ++j) {
    int idx = base + j;
    if (idx < NN) {
      cursor[idx] = run;
      run += v[j];
      rptr[idx + 1] = run;
    }
  }
}

__global__ void k_fill(const int* __restrict__ ei, int* __restrict__ cursor,
                       int* __restrict__ csrc) {
  int e = blockIdx.x * blockDim.x + threadIdx.x;
  if (e >= ET) return;
  int s, d;
  if (e < NE) { s = ei[e]; d = ei[NE + e]; } else { s = d = e - NE; }
  int p = atomicAdd(&cursor[d], 1);
  csrc[p] = s;
}

// ---------------- GEMM + fused attention logits -----------------------------
__global__ __launch_bounds__(256) void k_gemm(const _Float16* __restrict__ A,
                                              const _Float16* __restrict__ B,
                                              _Float16* __restrict__ C,
                                              const float* __restrict__ a_src,
                                              const float* __restrict__ a_dst,
                                              float* __restrict__ als,
                                              float* __restrict__ ald,
                                              int M, int N, int K, int gx,
                                              int H, int Ch) {
  const int nb = gridDim.x;
  const int q = nb >> 3, r = nb & 7;
  const int xcd = blockIdx.x & 7, kk = blockIdx.x >> 3;
  const int l = (xcd < r) ? (xcd * (q + 1) + kk) : (r * (q + 1) + (xcd - r) * q + kk);
  const int bx = l % gx, by = l / gx;

  __shared__ __align__(16) _Float16 Al[128 * 32];
  __shared__ __align__(16) _Float16 Bl[128 * 32];
  const int tid = threadIdx.x;
  const int wave = tid >> 6, lane = tid & 63;
  const int wm = wave >> 1, wn = wave & 1;
  const int m0 = by * 128, n0 = bx * 128;
  const int fr = lane & 15, fk = (lane >> 4) * 8;
  f32x4 acc[4][4] = {};

  for (int k0 = 0; k0 < K; k0 += 32) {
#pragma unroll
    for (int c = 0; c < 2; ++c) {
      int s = (wave * 2 + c) * 64 + lane;       // 16B slot id, 0..511
      int row = s >> 2, col = (s & 3) * 8;
      int ra = m0 + row; if (ra > M - 1) ra = M - 1;
      int rb = n0 + row; if (rb > N - 1) rb = N - 1;
      gload_lds16(A + (size_t)ra * K + k0 + col, &Al[(size_t)(wave * 2 + c) * 512]);
      gload_lds16(B + (size_t)rb * K + k0 + col, &Bl[(size_t)(wave * 2 + c) * 512]);
    }
    __syncthreads();
    f16x8 af[4], bf[4];
#pragma unroll
    for (int i = 0; i < 4; ++i) {
      af[i] = *(const f16x8*)&Al[(wm * 64 + i * 16 + fr) * 32 + fk];
      bf[i] = *(const f16x8*)&Bl[(wn * 64 + i * 16 + fr) * 32 + fk];
    }
#pragma unroll
    for (int mi = 0; mi < 4; ++mi)
#pragma unroll
      for (int ni = 0; ni < 4; ++ni)
        acc[mi][ni] = __builtin_amdgcn_mfma_f32_16x16x32_f16(af[mi], bf[ni], acc[mi][ni], 0, 0, 0);
    __syncthreads();
  }

  const int r0 = (lane >> 4) * 4, cn = lane & 15;

  // ---- store h tile (f16) ----
#pragma unroll
  for (int mi = 0; mi < 4; ++mi)
#pragma unroll
    for (int ni = 0; ni < 4; ++ni) {
      int gm = m0 + wm * 64 + mi * 16 + r0;
      int gn = n0 + wn * 64 + ni * 16 + cn;
      if (gn < N) {
#pragma unroll
        for (int rr = 0; rr < 4; ++rr)
          if (gm + rr < M) C[(size_t)(gm + rr) * N + gn] = (_Float16)acc[mi][ni][rr];
      }
    }

  // ---- fused logits: this wave's 64-col span lies in exactly one head ----
  const int colbase = n0 + wn * 64;
  if (colbase < N) {
    const int hd = colbase / Ch;
    const int cin = colbase % Ch;
    float asv[4], adv[4];
#pragma unroll
    for (int ni = 0; ni < 4; ++ni) {
      int cc = colbase + ni * 16 + cn;
      bool ok = cc < N;
      int ci = hd * Ch + cin + ni * 16 + cn;
      asv[ni] = ok ? a_src[ci] : 0.f;
      adv[ni] = ok ? a_dst[ci] : 0.f;
    }
#pragma unroll
    for (int mi = 0; mi < 4; ++mi) {
#pragma unroll
      for (int rr = 0; rr < 4; ++rr) {
        float sv = 0.f, dv = 0.f;
#pragma unroll
        for (int ni = 0; ni < 4; ++ni) {
          sv += acc[mi][ni][rr] * asv[ni];
          dv += acc[mi][ni][rr] * adv[ni];
        }
#pragma unroll
        for (int off = 1; off < 16; off <<= 1) {
          sv += __shfl_xor(sv, off);
          dv += __shfl_xor(dv, off);
        }
        if ((lane & 15) == 0) {
          int gm = m0 + wm * 64 + mi * 16 + r0 + rr;
          if (gm < M) {
            atomicAdd(&als[gm * H + hd], sv);
            atomicAdd(&ald[gm * H + hd], dv);
          }
        }
      }
    }
  }
}

// ---------------- fused softmax + aggregation (wave per node) ---------------
template <int H, int C, int MODE>
__global__ __launch_bounds__(256) void k_aggw(
    const _Float16* __restrict__ h, const float* __restrict__ als,
    const float* __restrict__ ald, const int* __restrict__ rptr,
    const int* __restrict__ csrc, const float* __restrict__ bias,
    _Float16* __restrict__ oh, float* __restrict__ of, int nbase) {
  constexpr int HC = H * C;
  constexpr int CPL = HC / 64;     // channels per lane: 16 (L1) or 8 (L2)
  constexpr int NV = CPL / 8;      // f16x8 loads per lane per row
  const int wave = threadIdx.x >> 6, lane = threadIdx.x & 63;
  const int n = nbase + blockIdx.x * 4 + wave;
  const int c0 = lane * CPL;
  const int hd = c0 / C;
  const float aldn = ald[n * H + hd];
  const int e0 = rptr[n], e1 = rptr[n + 1];
  float acc[CPL];
#pragma unroll
  for (int j = 0; j < CPL; ++j) acc[j] = 0.f;
  float den = 0.f;

  // two-stage register pipeline (raw als value carried; exp at consume)
  float lA = 0.f, lB = 0.f;
  f16x8 hA[NV], hB[NV];

#define LD_ROW(I, L, HV)                                                     \
  do {                                                                       \
    int _i = (I);                                                            \
    if (_i < e1) {                                                           \
      int _s = csrc[_i];                                                     \
      (L) = als[_s * H + hd];                                                \
      const _Float16* _hp = h + (size_t)_s * HC + c0;                        \
      _Pragma("unroll")                                                      \
      for (int _v = 0; _v < NV; ++_v) (HV)[_v] = *(const f16x8*)(_hp + _v * 8); \
    }                                                                        \
  } while (0)

  LD_ROW(e0, lA, hA);
  LD_ROW(e0 + 1, lB, hB);

  for (int i = e0; i < e1; i += 2) {
    {
      float v = lA + aldn;
      f16x8 t[NV];
#pragma unroll
      for (int vv = 0; vv < NV; ++vv) t[vv] = hA[vv];
      LD_ROW(i + 2, lA, hA);
      v = v > 0.f ? v : NEG_SLOPE * v;
      float xv = __expf(v);
      den += xv;
#pragma unroll
      for (int vv = 0; vv < NV; ++vv)
#pragma unroll
        for (int j = 0; j < 8; ++j) acc[vv * 8 + j] += xv * (float)t[vv][j];
    }
    if (i + 1 < e1) {
      float v = lB + aldn;
      f16x8 t[NV];
#pragma unroll
      for (int vv = 0; vv < NV; ++vv) t[vv] = hB[vv];
      LD_ROW(i + 3, lB, hB);
      v = v > 0.f ? v : NEG_SLOPE * v;
      float xv = __expf(v);
      den += xv;
#pragma unroll
      for (int vv = 0; vv < NV; ++vv)
#pragma unroll
        for (int j = 0; j < 8; ++j) acc[vv * 8 + j] += xv * (float)t[vv][j];
    }
  }
#undef LD_ROW

  float invd = 1.f / den;
#pragma unroll
  for (int v = 0; v < NV; ++v) {
    f16x8 o;
#pragma unroll
    for (int j = 0; j < 8; ++j) {
      float r = acc[v * 8 + j] * invd + bias[c0 + v * 8 + j];
      o[j] = (_Float16)(r > 0.f ? r : 0.f);
    }
    __builtin_nontemporal_store(o, (f16x8*)&oh[(size_t)n * HC + c0 + v * 8]);
  }
}

// last layer: H=1, C=64, tanh output (f32); 4 nodes per block (wave per node)
__global__ __launch_bounds__(256) void k_agg_last(
    const _Float16* __restrict__ h, const float* __restrict__ als,
    const float* __restrict__ ald, const int* __restrict__ rptr,
    const int* __restrict__ csrc, const float* __restrict__ bias,
    float* __restrict__ of) {
  int wave = threadIdx.x >> 6, t = threadIdx.x & 63;
  int n = blockIdx.x * 4 + wave;
  float acc = 0.f, den = 0.f;
  float aldn = ald[n];
  int e0 = rptr[n], e1 = rptr[n + 1];
  for (int i = e0; i < e1; ++i) {
    int s = csrc[i];
    float v = als[s] + aldn;
    v = v > 0.f ? v : NEG_SLOPE * v;
    float xv = __expf(v);
    den += xv;
    acc += xv * (float)h[(size_t)s * 64 + t];
  }
  of[(size_t)n * 64 + t] = tanhf(acc / den + bias[t]);
}

// ---------------- host side -------------------------------------------------
static inline size_t alup(size_t x) { return (x + 255) & ~(size_t)255; }

struct Scratch {
  _Float16* xb; _Float16* wtb1; _Float16* wtb2; _Float16* wtb3; _Float16* h;
  float* zb;   // als1,ald1,als2,ald2,als3,ald3 contiguous (NN*18 floats)
  int* cnt; int* rptr; int* cursor; int* csrc;
};

static void run_layer(hipStream_t stream, const Scratch& S, const _Float16* xin,
                      const _Float16* wtb, float* als, float* ald,
                      int K, int N, int H, int C,
                      const float* as_, const float* ad_, const float* bias,
                      int mode, _Float16* oh, float* of) {
  int gx = (N + 127) / 128, gy = (NN + 127) / 128;
  k_gemm<<<gx * gy, 256, 0, stream>>>(xin, wtb, S.h, as_, ad_, als, ald,
                                      NN, N, K, gx, H, C);
  if (mode == 0) {
    if (C == 256) {
      // split into two half-grids (diagnostic: surfaces 2nd-tier dispatches)
      k_aggw<4, 256, 0><<<NN / 8, 256, 0, stream>>>(S.h, als, ald, S.rptr, S.csrc, bias, oh, of, 0);
      k_aggw<4, 256, 0><<<NN / 8, 256, 0, stream>>>(S.h, als, ald, S.rptr, S.csrc, bias, oh, of, NN / 2);
    } else if (C == 128) {
      k_aggw<4, 128, 0><<<NN / 4, 256, 0, stream>>>(S.h, als, ald, S.rptr, S.csrc, bias, oh, of, 0);
    }
  } else {
    k_agg_last<<<NN / 4, 256, 0, stream>>>(S.h, als, ald, S.rptr, S.csrc, bias, of);
  }
}

extern "C" void kernel_launch(void* const* d_in, const int* in_sizes, int n_in,
                              void* d_out, int out_size, void* d_ws, size_t ws_size,
                              hipStream_t stream) {
  const float* x   = (const float*)d_in[0];
  const int*   ei  = (const int*)d_in[1];
  const float* W1  = (const float*)d_in[2];
  const float* a1s = (const float*)d_in[3];
  const float* a1d = (const float*)d_in[4];
  const float* b1  = (const float*)d_in[5];
  const float* W2  = (const float*)d_in[6];
  const float* a2s = (const float*)d_in[7];
  const float* a2d = (const float*)d_in[8];
  const float* b2  = (const float*)d_in[9];
  const float* W3  = (const float*)d_in[10];
  const float* a3s = (const float*)d_in[11];
  const float* a3d = (const float*)d_in[12];
  const float* b3  = (const float*)d_in[13];
  float* out = (float*)d_out;

  char* p = (char*)d_ws;
  Scratch S;
  S.xb   = (_Float16*)p; p += alup((size_t)NN * 1024 * 2);
  S.wtb1 = (_Float16*)p; p += alup((size_t)1024 * 768 * 2);
  S.wtb2 = (_Float16*)p; p += alup((size_t)512 * 1024 * 2);
  S.wtb3 = (_Float16*)p; p += alup((size_t)64 * 512 * 2);
  S.h    = (_Float16*)p; p += alup((size_t)NN * 1024 * 2);
  S.zb   = (float*)p;    p += alup((size_t)NN * 18 * 4);
  S.cnt  = (int*)p;      p += alup((size_t)NN * 4);
  S.rptr = (int*)p;      p += alup((size_t)(NN + 1) * 4);
  S.cursor=(int*)p;      p += alup((size_t)NN * 4);
  S.csrc = (int*)p;      p += alup((size_t)ET * 4);

  float* als1 = S.zb;
  float* ald1 = als1 + NN * 4;
  float* als2 = ald1 + NN * 4;
  float* ald2 = als2 + NN * 4;
  float* als3 = ald2 + NN * 4;
  float* ald3 = als3 + NN;

  // fused init: 3 weight transposes + cnt=0 + als/ald=0 + x->f16
  k_init<<<1312 + 1024, 256, 0, stream>>>(x, S.xb, S.cnt, S.zb, NN * 18,
                                          W1, S.wtb1, W2, S.wtb2, W3, S.wtb3);
  // CSR build (per-launch, deterministic work)
  k_count<<<(ET + 255) / 256, 256, 0, stream>>>(ei, S.cnt);
  k_scan<<<1, 1024, 0, stream>>>(S.cnt, S.rptr, S.cursor);
  k_fill<<<(ET + 255) / 256, 256, 0, stream>>>(ei, S.cursor, S.csrc);

  // layer 1: K=768, H=4, C=256, relu -> f16
  run_layer(stream, S, S.xb, S.wtb1, als1, ald1, 768, 1024, 4, 256, a1s, a1d, b1, 0, S.xb, nullptr);
  // layer 2: K=1024, H=4, C=128, relu -> f16
  run_layer(stream, S, S.xb, S.wtb2, als2, ald2, 1024, 512, 4, 128, a2s, a2d, b2, 0, S.xb, nullptr);
  // layer 3: K=512, H=1, C=64, tanh -> f32 out
  run_layer(stream, S, S.xb, S.wtb3, als3, ald3, 512, 64, 1, 64, a3s, a3d, b3, 1, nullptr, out);
}

// Round 11
// 431.976 us; speedup vs baseline: 1.0207x; 1.0207x over previous
//
#include <hip/hip_runtime.h>
#include <hip/hip_bf16.h>

#define NN 20000
#define NE 320000
#define ET 340000            // NE + NN self loops
#define NEG_SLOPE 0.2f

typedef __attribute__((ext_vector_type(8))) _Float16 f16x8;
typedef __attribute__((ext_vector_type(4))) _Float16 f16x4;
typedef __attribute__((ext_vector_type(4))) float f32x4;

typedef __attribute__((address_space(3))) unsigned int lds_u32_t;
typedef __attribute__((address_space(1))) unsigned int glb_u32_t;

__device__ __forceinline__ void gload_lds16(const void* g, void* l) {
  __builtin_amdgcn_global_load_lds((const glb_u32_t*)g, (lds_u32_t*)l, 16, 0, 0);
}

// ---- fused init: 3 weight transposes + zero cnt + zero als/ald + x->f16 ----
__global__ __launch_bounds__(256) void k_init(
    const float* __restrict__ x, _Float16* __restrict__ xb,
    int* __restrict__ cnt, float* __restrict__ zb, int nz,
    const float* __restrict__ W1, _Float16* __restrict__ Wt1,
    const float* __restrict__ W2, _Float16* __restrict__ Wt2,
    const float* __restrict__ W3, _Float16* __restrict__ Wt3) {
  __shared__ float tile[32][33];
  if (blockIdx.x < 1312) {
    int b = blockIdx.x;
    const float* W; _Float16* Wt; int K, N, bk, bn;
    if (b < 768)       { W = W1; Wt = Wt1; K = 768;  N = 1024; bn = (b % 32) * 32; bk = (b / 32) * 32; }
    else if (b < 1280) { b -= 768;  W = W2; Wt = Wt2; K = 1024; N = 512; bn = (b % 16) * 32; bk = (b / 16) * 32; }
    else               { b -= 1280; W = W3; Wt = Wt3; K = 512;  N = 64;  bn = (b % 2) * 32;  bk = (b / 2) * 32; }
    int tx = threadIdx.x & 31, ty = threadIdx.x >> 5;  // 32 x 8
#pragma unroll
    for (int r = ty; r < 32; r += 8)
      tile[r][tx] = W[(size_t)(bk + r) * N + bn + tx];
    __syncthreads();
#pragma unroll
    for (int r = ty; r < 32; r += 8)
      Wt[(size_t)(bn + r) * K + bk + tx] = (_Float16)tile[tx][r];
    return;
  }
  const int stride = (gridDim.x - 1312) * blockDim.x;
  const int i0 = (blockIdx.x - 1312) * blockDim.x + threadIdx.x;
  for (int i = i0; i < NN; i += stride) cnt[i] = 0;
  for (int i = i0; i < nz; i += stride) zb[i] = 0.f;
  const int n4 = NN * 768 / 4;
  for (int i = i0; i < n4; i += stride) {
    f32x4 v = *(const f32x4*)&x[i * 4];
    f16x4 h = { (_Float16)v.x, (_Float16)v.y, (_Float16)v.z, (_Float16)v.w };
    *(f16x4*)&xb[i * 4] = h;
  }
}

// ---------------- CSR build -------------------------------------------------
__global__ void k_count(const int* __restrict__ ei, int* __restrict__ cnt) {
  int e = blockIdx.x * blockDim.x + threadIdx.x;
  if (e >= ET) return;
  int d = (e < NE) ? ei[NE + e] : (e - NE);
  atomicAdd(&cnt[d], 1);
}

// one-pass single-block scan: 1024 threads x 20 elements each
__global__ __launch_bounds__(1024) void k_scan(const int* __restrict__ cnt,
                                               int* __restrict__ rptr,
                                               int* __restrict__ cursor) {
  const int CH = 20;  // 1024*20 = 20480 >= NN
  int t = threadIdx.x, lane = t & 63, wid = t >> 6;
  int base = t * CH;
  int v[CH];
  int sum = 0;
#pragma unroll
  for (int j = 0; j < CH; ++j) {
    int idx = base + j;
    v[j] = (idx < NN) ? cnt[idx] : 0;
    sum += v[j];
  }
  int ws = sum;  // inclusive wave scan
#pragma unroll
  for (int off = 1; off < 64; off <<= 1) {
    int u = __shfl_up(ws, off);
    if (lane >= off) ws += u;
  }
  __shared__ int wsum[16];
  __shared__ int wpre[16];
  if (lane == 63) wsum[wid] = ws;
  __syncthreads();
  if (t == 0) {
    int acc = 0;
#pragma unroll
    for (int w = 0; w < 16; ++w) { wpre[w] = acc; acc += wsum[w]; }
  }
  __syncthreads();
  int run = wpre[wid] + ws - sum;  // exclusive prefix of this chunk
  if (t == 0) rptr[0] = 0;
#pragma unroll
  for (int j = 0; j < CH; ++j) {
    int idx = base + j;
    if (idx < NN) {
      cursor[idx] = run;
      run += v[j];
      rptr[idx + 1] = run;
    }
  }
}

__global__ void k_fill(const int* __restrict__ ei, int* __restrict__ cursor,
                       int* __restrict__ csrc) {
  int e = blockIdx.x * blockDim.x + threadIdx.x;
  if (e >= ET) return;
  int s, d;
  if (e < NE) { s = ei[e]; d = ei[NE + e]; } else { s = d = e - NE; }
  int p = atomicAdd(&cursor[d], 1);
  csrc[p] = s;
}

// ---------------- GEMM + fused attention logits -----------------------------
// 2-phase double-buffered staging (T3 minimum pattern) + bank-conflict-free
// LDS via source-permuted staging (rule #21: linear LDS dest, global source
// column chunk XOR'd with (row>>1)&3, reads XOR'd identically -> 2-way, free).
__global__ __launch_bounds__(256) void k_gemm(const _Float16* __restrict__ A,
                                              const _Float16* __restrict__ B,
                                              _Float16* __restrict__ C,
                                              const float* __restrict__ a_src,
                                              const float* __restrict__ a_dst,
                                              float* __restrict__ als,
                                              float* __restrict__ ald,
                                              int M, int N, int K, int gx,
                                              int H, int Ch) {
  const int nb = gridDim.x;
  const int q = nb >> 3, r = nb & 7;
  const int xcd = blockIdx.x & 7, kk = blockIdx.x >> 3;
  const int l = (xcd < r) ? (xcd * (q + 1) + kk) : (r * (q + 1) + (xcd - r) * q + kk);
  const int bx = l % gx, by = l / gx;

  __shared__ __align__(16) _Float16 Al[2][128 * 32];
  __shared__ __align__(16) _Float16 Bl[2][128 * 32];
  const int tid = threadIdx.x;
  const int wave = tid >> 6, lane = tid & 63;
  const int wm = wave >> 1, wn = wave & 1;
  const int m0 = by * 128, n0 = bx * 128;
  const int fr = lane & 15;
  const int fx = ((lane >> 4) ^ ((fr >> 1) & 3)) * 8;   // swizzled k-chunk
  f32x4 acc[4][4] = {};

#define STAGE(BUF, K0)                                                        \
  do {                                                                        \
    _Pragma("unroll")                                                         \
    for (int c = 0; c < 2; ++c) {                                             \
      int s = (wave * 2 + c) * 64 + lane;                                     \
      int row = s >> 2;                                                       \
      int col = ((s & 3) ^ ((s >> 3) & 3)) * 8;                               \
      int ra = m0 + row; if (ra > M - 1) ra = M - 1;                          \
      int rb = n0 + row; if (rb > N - 1) rb = N - 1;                          \
      gload_lds16(A + (size_t)ra * K + (K0) + col, &Al[BUF][(wave * 2 + c) * 512]); \
      gload_lds16(B + (size_t)rb * K + (K0) + col, &Bl[BUF][(wave * 2 + c) * 512]); \
    }                                                                         \
  } while (0)

#define COMPUTE(BUF)                                                          \
  do {                                                                        \
    f16x8 af[4], bf[4];                                                       \
    _Pragma("unroll")                                                         \
    for (int i = 0; i < 4; ++i) {                                             \
      af[i] = *(const f16x8*)&Al[BUF][(wm * 64 + i * 16 + fr) * 32 + fx];     \
      bf[i] = *(const f16x8*)&Bl[BUF][(wn * 64 + i * 16 + fr) * 32 + fx];     \
    }                                                                         \
    _Pragma("unroll")                                                         \
    for (int mi = 0; mi < 4; ++mi)                                            \
      _Pragma("unroll")                                                       \
      for (int ni = 0; ni < 4; ++ni)                                          \
        acc[mi][ni] = __builtin_amdgcn_mfma_f32_16x16x32_f16(af[mi], bf[ni], acc[mi][ni], 0, 0, 0); \
  } while (0)

  STAGE(0, 0);
  __syncthreads();
  int cur = 0;
  for (int k0 = 32; k0 < K; k0 += 32) {
    STAGE(cur ^ 1, k0);     // prefetch next K-chunk while computing current
    COMPUTE(cur);
    __syncthreads();        // drains vmcnt: next buffer ready
    cur ^= 1;
  }
  COMPUTE(cur);

#undef STAGE
#undef COMPUTE

  const int r0 = (lane >> 4) * 4, cn = lane & 15;

  // ---- store h tile (f16) ----
#pragma unroll
  for (int mi = 0; mi < 4; ++mi)
#pragma unroll
    for (int ni = 0; ni < 4; ++ni) {
      int gm = m0 + wm * 64 + mi * 16 + r0;
      int gn = n0 + wn * 64 + ni * 16 + cn;
      if (gn < N) {
#pragma unroll
        for (int rr = 0; rr < 4; ++rr)
          if (gm + rr < M) C[(size_t)(gm + rr) * N + gn] = (_Float16)acc[mi][ni][rr];
      }
    }

  // ---- fused logits: this wave's 64-col span lies in exactly one head ----
  const int colbase = n0 + wn * 64;
  if (colbase < N) {
    const int hd = colbase / Ch;
    const int cin = colbase % Ch;
    float asv[4], adv[4];
#pragma unroll
    for (int ni = 0; ni < 4; ++ni) {
      int cc = colbase + ni * 16 + cn;
      bool ok = cc < N;
      int ci = hd * Ch + cin + ni * 16 + cn;
      asv[ni] = ok ? a_src[ci] : 0.f;
      adv[ni] = ok ? a_dst[ci] : 0.f;
    }
#pragma unroll
    for (int mi = 0; mi < 4; ++mi) {
#pragma unroll
      for (int rr = 0; rr < 4; ++rr) {
        float sv = 0.f, dv = 0.f;
#pragma unroll
        for (int ni = 0; ni < 4; ++ni) {
          sv += acc[mi][ni][rr] * asv[ni];
          dv += acc[mi][ni][rr] * adv[ni];
        }
#pragma unroll
        for (int off = 1; off < 16; off <<= 1) {
          sv += __shfl_xor(sv, off);
          dv += __shfl_xor(dv, off);
        }
        if ((lane & 15) == 0) {
          int gm = m0 + wm * 64 + mi * 16 + r0 + rr;
          if (gm < M) {
            atomicAdd(&als[gm * H + hd], sv);
            atomicAdd(&ald[gm * H + hd], dv);
          }
        }
      }
    }
  }
}

// ---------------- fused softmax + aggregation (wave per node) ---------------
template <int H, int C, int MODE>
__global__ __launch_bounds__(256) void k_aggw(
    const _Float16* __restrict__ h, const float* __restrict__ als,
    const float* __restrict__ ald, const int* __restrict__ rptr,
    const int* __restrict__ csrc, const float* __restrict__ bias,
    _Float16* __restrict__ oh, float* __restrict__ of) {
  constexpr int HC = H * C;
  constexpr int CPL = HC / 64;     // channels per lane: 16 (L1) or 8 (L2)
  constexpr int NV = CPL / 8;      // f16x8 loads per lane per row
  const int wave = threadIdx.x >> 6, lane = threadIdx.x & 63;
  const int n = blockIdx.x * 4 + wave;
  const int c0 = lane * CPL;
  const int hd = c0 / C;
  const float aldn = ald[n * H + hd];
  const int e0 = rptr[n], e1 = rptr[n + 1];
  float acc[CPL];
#pragma unroll
  for (int j = 0; j < CPL; ++j) acc[j] = 0.f;
  float den = 0.f;

  // two-stage register pipeline (raw als value carried; exp at consume)
  float lA = 0.f, lB = 0.f;
  f16x8 hA[NV], hB[NV];

#define LD_ROW(I, L, HV)                                                     \
  do {                                                                       \
    int _i = (I);                                                            \
    if (_i < e1) {                                                           \
      int _s = csrc[_i];                                                     \
      (L) = als[_s * H + hd];                                                \
      const _Float16* _hp = h + (size_t)_s * HC + c0;                        \
      _Pragma("unroll")                                                      \
      for (int _v = 0; _v < NV; ++_v) (HV)[_v] = *(const f16x8*)(_hp + _v * 8); \
    }                                                                        \
  } while (0)

  LD_ROW(e0, lA, hA);
  LD_ROW(e0 + 1, lB, hB);

  for (int i = e0; i < e1; i += 2) {
    {
      float v = lA + aldn;
      f16x8 t[NV];
#pragma unroll
      for (int vv = 0; vv < NV; ++vv) t[vv] = hA[vv];
      LD_ROW(i + 2, lA, hA);
      v = v > 0.f ? v : NEG_SLOPE * v;
      float xv = __expf(v);
      den += xv;
#pragma unroll
      for (int vv = 0; vv < NV; ++vv)
#pragma unroll
        for (int j = 0; j < 8; ++j) acc[vv * 8 + j] += xv * (float)t[vv][j];
    }
    if (i + 1 < e1) {
      float v = lB + aldn;
      f16x8 t[NV];
#pragma unroll
      for (int vv = 0; vv < NV; ++vv) t[vv] = hB[vv];
      LD_ROW(i + 3, lB, hB);
      v = v > 0.f ? v : NEG_SLOPE * v;
      float xv = __expf(v);
      den += xv;
#pragma unroll
      for (int vv = 0; vv < NV; ++vv)
#pragma unroll
        for (int j = 0; j < 8; ++j) acc[vv * 8 + j] += xv * (float)t[vv][j];
    }
  }
#undef LD_ROW

  float invd = 1.f / den;
#pragma unroll
  for (int v = 0; v < NV; ++v) {
    f16x8 o;
#pragma unroll
    for (int j = 0; j < 8; ++j) {
      float r = acc[v * 8 + j] * invd + bias[c0 + v * 8 + j];
      o[j] = (_Float16)(r > 0.f ? r : 0.f);
    }
    __builtin_nontemporal_store(o, (f16x8*)&oh[(size_t)n * HC + c0 + v * 8]);
  }
}

// last layer: H=1, C=64, tanh output (f32); 4 nodes per block (wave per node)
__global__ __launch_bounds__(256) void k_agg_last(
    const _Float16* __restrict__ h, const float* __restrict__ als,
    const float* __restrict__ ald, const int* __restrict__ rptr,
    const int* __restrict__ csrc, const float* __restrict__ bias,
    float* __restrict__ of) {
  int wave = threadIdx.x >> 6, t = threadIdx.x & 63;
  int n = blockIdx.x * 4 + wave;
  float acc = 0.f, den = 0.f;
  float aldn = ald[n];
  int e0 = rptr[n], e1 = rptr[n + 1];
  for (int i = e0; i < e1; ++i) {
    int s = csrc[i];
    float v = als[s] + aldn;
    v = v > 0.f ? v : NEG_SLOPE * v;
    float xv = __expf(v);
    den += xv;
    acc += xv * (float)h[(size_t)s * 64 + t];
  }
  of[(size_t)n * 64 + t] = tanhf(acc / den + bias[t]);
}

// ---------------- host side -------------------------------------------------
static inline size_t alup(size_t x) { return (x + 255) & ~(size_t)255; }

struct Scratch {
  _Float16* xb; _Float16* wtb1; _Float16* wtb2; _Float16* wtb3; _Float16* h;
  float* zb;   // als1,ald1,als2,ald2,als3,ald3 contiguous (NN*18 floats)
  int* cnt; int* rptr; int* cursor; int* csrc;
};

static void run_layer(hipStream_t stream, const Scratch& S, const _Float16* xin,
                      const _Float16* wtb, float* als, float* ald,
                      int K, int N, int H, int C,
                      const float* as_, const float* ad_, const float* bias,
                      int mode, _Float16* oh, float* of) {
  int gx = (N + 127) / 128, gy = (NN + 127) / 128;
  k_gemm<<<gx * gy, 256, 0, stream>>>(xin, wtb, S.h, as_, ad_, als, ald,
                                      NN, N, K, gx, H, C);
  if (mode == 0) {
    if (C == 256)      k_aggw<4, 256, 0><<<NN / 4, 256, 0, stream>>>(S.h, als, ald, S.rptr, S.csrc, bias, oh, of);
    else if (C == 128) k_aggw<4, 128, 0><<<NN / 4, 256, 0, stream>>>(S.h, als, ald, S.rptr, S.csrc, bias, oh, of);
  } else {
    k_agg_last<<<NN / 4, 256, 0, stream>>>(S.h, als, ald, S.rptr, S.csrc, bias, of);
  }
}

extern "C" void kernel_launch(void* const* d_in, const int* in_sizes, int n_in,
                              void* d_out, int out_size, void* d_ws, size_t ws_size,
                              hipStream_t stream) {
  const float* x   = (const float*)d_in[0];
  const int*   ei  = (const int*)d_in[1];
  const float* W1  = (const float*)d_in[2];
  const float* a1s = (const float*)d_in[3];
  const float* a1d = (const float*)d_in[4];
  const float* b1  = (const float*)d_in[5];
  const float* W2  = (const float*)d_in[6];
  const float* a2s = (const float*)d_in[7];
  const float* a2d = (const float*)d_in[8];
  const float* b2  = (const float*)d_in[9];
  const float* W3  = (const float*)d_in[10];
  const float* a3s = (const float*)d_in[11];
  const float* a3d = (const float*)d_in[12];
  const float* b3  = (const float*)d_in[13];
  float* out = (float*)d_out;

  char* p = (char*)d_ws;
  Scratch S;
  S.xb   = (_Float16*)p; p += alup((size_t)NN * 1024 * 2);
  S.wtb1 = (_Float16*)p; p += alup((size_t)1024 * 768 * 2);
  S.wtb2 = (_Float16*)p; p += alup((size_t)512 * 1024 * 2);
  S.wtb3 = (_Float16*)p; p += alup((size_t)64 * 512 * 2);
  S.h    = (_Float16*)p; p += alup((size_t)NN * 1024 * 2);
  S.zb   = (float*)p;    p += alup((size_t)NN * 18 * 4);
  S.cnt  = (int*)p;      p += alup((size_t)NN * 4);
  S.rptr = (int*)p;      p += alup((size_t)(NN + 1) * 4);
  S.cursor=(int*)p;      p += alup((size_t)NN * 4);
  S.csrc = (int*)p;      p += alup((size_t)ET * 4);

  float* als1 = S.zb;
  float* ald1 = als1 + NN * 4;
  float* als2 = ald1 + NN * 4;
  float* ald2 = als2 + NN * 4;
  float* als3 = ald2 + NN * 4;
  float* ald3 = als3 + NN;

  // fused init: 3 weight transposes + cnt=0 + als/ald=0 + x->f16
  k_init<<<1312 + 1024, 256, 0, stream>>>(x, S.xb, S.cnt, S.zb, NN * 18,
                                          W1, S.wtb1, W2, S.wtb2, W3, S.wtb3);
  // CSR build (per-launch, deterministic work)
  k_count<<<(ET + 255) / 256, 256, 0, stream>>>(ei, S.cnt);
  k_scan<<<1, 1024, 0, stream>>>(S.cnt, S.rptr, S.cursor);
  k_fill<<<(ET + 255) / 256, 256, 0, stream>>>(ei, S.cursor, S.csrc);

  // layer 1: K=768, H=4, C=256, relu -> f16
  run_layer(stream, S, S.xb, S.wtb1, als1, ald1, 768, 1024, 4, 256, a1s, a1d, b1, 0, S.xb, nullptr);
  // layer 2: K=1024, H=4, C=128, relu -> f16
  run_layer(stream, S, S.xb, S.wtb2, als2, ald2, 1024, 512, 4, 128, a2s, a2d, b2, 0, S.xb, nullptr);
  // layer 3: K=512, H=1, C=64, tanh -> f32 out
  run_layer(stream, S, S.xb, S.wtb3, als3, ald3, 512, 64, 1, 64, a3s, a3d, b3, 1, nullptr, out);
}

// Round 12
// 423.335 us; speedup vs baseline: 1.0415x; 1.0204x over previous
//
#include <hip/hip_runtime.h>
#include <hip/hip_bf16.h>

#define NN 20000
#define NE 320000
#define ET 340000            // NE + NN self loops
#define NEG_SLOPE 0.2f

typedef __attribute__((ext_vector_type(8))) _Float16 f16x8;
typedef __attribute__((ext_vector_type(4))) _Float16 f16x4;
typedef __attribute__((ext_vector_type(4))) float f32x4;

typedef __attribute__((address_space(3))) unsigned int lds_u32_t;
typedef __attribute__((address_space(1))) unsigned int glb_u32_t;

__device__ __forceinline__ void gload_lds16(const void* g, void* l) {
  __builtin_amdgcn_global_load_lds((const glb_u32_t*)g, (lds_u32_t*)l, 16, 0, 0);
}

// ---- fused init: 3 weight transposes + zero cnt + zero als/ald + x->f16 ----
__global__ __launch_bounds__(256) void k_init(
    const float* __restrict__ x, _Float16* __restrict__ xb,
    int* __restrict__ cnt, float* __restrict__ zb, int nz,
    const float* __restrict__ W1, _Float16* __restrict__ Wt1,
    const float* __restrict__ W2, _Float16* __restrict__ Wt2,
    const float* __restrict__ W3, _Float16* __restrict__ Wt3) {
  __shared__ float tile[32][33];
  if (blockIdx.x < 1312) {
    int b = blockIdx.x;
    const float* W; _Float16* Wt; int K, N, bk, bn;
    if (b < 768)       { W = W1; Wt = Wt1; K = 768;  N = 1024; bn = (b % 32) * 32; bk = (b / 32) * 32; }
    else if (b < 1280) { b -= 768;  W = W2; Wt = Wt2; K = 1024; N = 512; bn = (b % 16) * 32; bk = (b / 16) * 32; }
    else               { b -= 1280; W = W3; Wt = Wt3; K = 512;  N = 64;  bn = (b % 2) * 32;  bk = (b / 2) * 32; }
    int tx = threadIdx.x & 31, ty = threadIdx.x >> 5;  // 32 x 8
#pragma unroll
    for (int r = ty; r < 32; r += 8)
      tile[r][tx] = W[(size_t)(bk + r) * N + bn + tx];
    __syncthreads();
#pragma unroll
    for (int r = ty; r < 32; r += 8)
      Wt[(size_t)(bn + r) * K + bk + tx] = (_Float16)tile[tx][r];
    return;
  }
  const int stride = (gridDim.x - 1312) * blockDim.x;
  const int i0 = (blockIdx.x - 1312) * blockDim.x + threadIdx.x;
  for (int i = i0; i < NN; i += stride) cnt[i] = 0;
  for (int i = i0; i < nz; i += stride) zb[i] = 0.f;
  const int n4 = NN * 768 / 4;
  for (int i = i0; i < n4; i += stride) {
    f32x4 v = *(const f32x4*)&x[i * 4];
    f16x4 h = { (_Float16)v.x, (_Float16)v.y, (_Float16)v.z, (_Float16)v.w };
    *(f16x4*)&xb[i * 4] = h;
  }
}

// ---------------- CSR build -------------------------------------------------
__global__ void k_count(const int* __restrict__ ei, int* __restrict__ cnt) {
  int e = blockIdx.x * blockDim.x + threadIdx.x;
  if (e >= ET) return;
  int d = (e < NE) ? ei[NE + e] : (e - NE);
  atomicAdd(&cnt[d], 1);
}

// one-pass single-block scan: 1024 threads x 20 elements each
__global__ __launch_bounds__(1024) void k_scan(const int* __restrict__ cnt,
                                               int* __restrict__ rptr,
                                               int* __restrict__ cursor) {
  const int CH = 20;  // 1024*20 = 20480 >= NN
  int t = threadIdx.x, lane = t & 63, wid = t >> 6;
  int base = t * CH;
  int v[CH];
  int sum = 0;
#pragma unroll
  for (int j = 0; j < CH; ++j) {
    int idx = base + j;
    v[j] = (idx < NN) ? cnt[idx] : 0;
    sum += v[j];
  }
  int ws = sum;  // inclusive wave scan
#pragma unroll
  for (int off = 1; off < 64; off <<= 1) {
    int u = __shfl_up(ws, off);
    if (lane >= off) ws += u;
  }
  __shared__ int wsum[16];
  __shared__ int wpre[16];
  if (lane == 63) wsum[wid] = ws;
  __syncthreads();
  if (t == 0) {
    int acc = 0;
#pragma unroll
    for (int w = 0; w < 16; ++w) { wpre[w] = acc; acc += wsum[w]; }
  }
  __syncthreads();
  int run = wpre[wid] + ws - sum;  // exclusive prefix of this chunk
  if (t == 0) rptr[0] = 0;
#pragma unroll
  for (int j = 0; j < CH; ++j) {
    int idx = base + j;
    if (idx < NN) {
      cursor[idx] = run;
      run += v[j];
      rptr[idx + 1] = run;
    }
  }
}

__global__ void k_fill(const int* __restrict__ ei, int* __restrict__ cursor,
                       int* __restrict__ csrc) {
  int e = blockIdx.x * blockDim.x + threadIdx.x;
  if (e >= ET) return;
  int s, d;
  if (e < NE) { s = ei[e]; d = ei[NE + e]; } else { s = d = e - NE; }
  int p = atomicAdd(&cursor[d], 1);
  csrc[p] = s;
}

// ---------------- GEMM + fused attention logits -----------------------------
// T3+T4 pipeline: 3 LDS buffers, depth-2 prefetch, counted s_waitcnt vmcnt(N)
// + raw s_barrier (loads stay in flight ACROSS barriers; never drain to 0 in
// steady state). Only VMEM in the loop is gload_lds (4/wave/stage) so the
// vmcnt arithmetic is exact: after staging t+2, 12 outstanding; vmcnt(8)
// retires the oldest 4 = buffer t's loads. Bank-conflict-free LDS reads via
// source-permuted staging (rule #21).
__global__ __launch_bounds__(256) void k_gemm(const _Float16* __restrict__ A,
                                              const _Float16* __restrict__ B,
                                              _Float16* __restrict__ C,
                                              const float* __restrict__ a_src,
                                              const float* __restrict__ a_dst,
                                              float* __restrict__ als,
                                              float* __restrict__ ald,
                                              int M, int N, int K, int gx,
                                              int H, int Ch) {
  const int nb = gridDim.x;
  const int q = nb >> 3, r = nb & 7;
  const int xcd = blockIdx.x & 7, kk = blockIdx.x >> 3;
  const int l = (xcd < r) ? (xcd * (q + 1) + kk) : (r * (q + 1) + (xcd - r) * q + kk);
  const int bx = l % gx, by = l / gx;

  __shared__ __align__(16) _Float16 Al[3][128 * 32];
  __shared__ __align__(16) _Float16 Bl[3][128 * 32];
  const int tid = threadIdx.x;
  const int wave = tid >> 6, lane = tid & 63;
  const int wm = wave >> 1, wn = wave & 1;
  const int m0 = by * 128, n0 = bx * 128;
  const int fr = lane & 15;
  const int fx = ((lane >> 4) ^ ((fr >> 1) & 3)) * 8;   // swizzled k-chunk
  f32x4 acc[4][4] = {};

#define STAGE(BUF, K0)                                                        \
  do {                                                                        \
    _Pragma("unroll")                                                         \
    for (int c = 0; c < 2; ++c) {                                             \
      int s = (wave * 2 + c) * 64 + lane;                                     \
      int row = s >> 2;                                                       \
      int col = ((s & 3) ^ ((s >> 3) & 3)) * 8;                               \
      int ra = m0 + row; if (ra > M - 1) ra = M - 1;                          \
      int rb = n0 + row; if (rb > N - 1) rb = N - 1;                          \
      gload_lds16(A + (size_t)ra * K + (K0) + col, &Al[BUF][(wave * 2 + c) * 512]); \
      gload_lds16(B + (size_t)rb * K + (K0) + col, &Bl[BUF][(wave * 2 + c) * 512]); \
    }                                                                         \
  } while (0)

#define COMPUTE(BUF)                                                          \
  do {                                                                        \
    f16x8 af[4], bf[4];                                                       \
    _Pragma("unroll")                                                         \
    for (int i = 0; i < 4; ++i) {                                             \
      af[i] = *(const f16x8*)&Al[BUF][(wm * 64 + i * 16 + fr) * 32 + fx];     \
      bf[i] = *(const f16x8*)&Bl[BUF][(wn * 64 + i * 16 + fr) * 32 + fx];     \
    }                                                                         \
    _Pragma("unroll")                                                         \
    for (int mi = 0; mi < 4; ++mi)                                            \
      _Pragma("unroll")                                                       \
      for (int ni = 0; ni < 4; ++ni)                                          \
        acc[mi][ni] = __builtin_amdgcn_mfma_f32_16x16x32_f16(af[mi], bf[ni], acc[mi][ni], 0, 0, 0); \
  } while (0)

  const int NT = K >> 5;
  STAGE(0, 0);
  STAGE(1, 32);
  for (int t = 0; t < NT; ++t) {
    const int b = t % 3;
    const int tp = t + 2;
    if (tp < NT) {
      STAGE(tp % 3, tp * 32);
      asm volatile("s_waitcnt vmcnt(8)" ::: "memory");   // buf t landed; 8 in flight
    } else if (t + 1 < NT) {
      asm volatile("s_waitcnt vmcnt(4)" ::: "memory");   // buf t landed; t+1 in flight
    } else {
      asm volatile("s_waitcnt vmcnt(0)" ::: "memory");   // last buffer
    }
    __builtin_amdgcn_s_barrier();   // all waves' buf-t loads landed
    COMPUTE(b);
    __builtin_amdgcn_s_barrier();   // buf (t+2)%3 safe to overwrite next iter
  }

#undef STAGE
#undef COMPUTE

  const int r0 = (lane >> 4) * 4, cn = lane & 15;

  // ---- store h tile (f16) ----
#pragma unroll
  for (int mi = 0; mi < 4; ++mi)
#pragma unroll
    for (int ni = 0; ni < 4; ++ni) {
      int gm = m0 + wm * 64 + mi * 16 + r0;
      int gn = n0 + wn * 64 + ni * 16 + cn;
      if (gn < N) {
#pragma unroll
        for (int rr = 0; rr < 4; ++rr)
          if (gm + rr < M) C[(size_t)(gm + rr) * N + gn] = (_Float16)acc[mi][ni][rr];
      }
    }

  // ---- fused logits: this wave's 64-col span lies in exactly one head ----
  const int colbase = n0 + wn * 64;
  if (colbase < N) {
    const int hd = colbase / Ch;
    const int cin = colbase % Ch;
    float asv[4], adv[4];
#pragma unroll
    for (int ni = 0; ni < 4; ++ni) {
      int cc = colbase + ni * 16 + cn;
      bool ok = cc < N;
      int ci = hd * Ch + cin + ni * 16 + cn;
      asv[ni] = ok ? a_src[ci] : 0.f;
      adv[ni] = ok ? a_dst[ci] : 0.f;
    }
#pragma unroll
    for (int mi = 0; mi < 4; ++mi) {
#pragma unroll
      for (int rr = 0; rr < 4; ++rr) {
        float sv = 0.f, dv = 0.f;
#pragma unroll
        for (int ni = 0; ni < 4; ++ni) {
          sv += acc[mi][ni][rr] * asv[ni];
          dv += acc[mi][ni][rr] * adv[ni];
        }
#pragma unroll
        for (int off = 1; off < 16; off <<= 1) {
          sv += __shfl_xor(sv, off);
          dv += __shfl_xor(dv, off);
        }
        if ((lane & 15) == 0) {
          int gm = m0 + wm * 64 + mi * 16 + r0 + rr;
          if (gm < M) {
            atomicAdd(&als[gm * H + hd], sv);
            atomicAdd(&ald[gm * H + hd], dv);
          }
        }
      }
    }
  }
}

// ---------------- fused softmax + aggregation (wave per node) ---------------
template <int H, int C, int MODE>
__global__ __launch_bounds__(256) void k_aggw(
    const _Float16* __restrict__ h, const float* __restrict__ als,
    const float* __restrict__ ald, const int* __restrict__ rptr,
    const int* __restrict__ csrc, const float* __restrict__ bias,
    _Float16* __restrict__ oh, float* __restrict__ of) {
  constexpr int HC = H * C;
  constexpr int CPL = HC / 64;     // channels per lane: 16 (L1) or 8 (L2)
  constexpr int NV = CPL / 8;      // f16x8 loads per lane per row
  const int wave = threadIdx.x >> 6, lane = threadIdx.x & 63;
  const int n = blockIdx.x * 4 + wave;
  const int c0 = lane * CPL;
  const int hd = c0 / C;
  const float aldn = ald[n * H + hd];
  const int e0 = rptr[n], e1 = rptr[n + 1];
  float acc[CPL];
#pragma unroll
  for (int j = 0; j < CPL; ++j) acc[j] = 0.f;
  float den = 0.f;

  // two-stage register pipeline (raw als value carried; exp at consume)
  float lA = 0.f, lB = 0.f;
  f16x8 hA[NV], hB[NV];

#define LD_ROW(I, L, HV)                                                     \
  do {                                                                       \
    int _i = (I);                                                            \
    if (_i < e1) {                                                           \
      int _s = csrc[_i];                                                     \
      (L) = als[_s * H + hd];                                                \
      const _Float16* _hp = h + (size_t)_s * HC + c0;                        \
      _Pragma("unroll")                                                      \
      for (int _v = 0; _v < NV; ++_v) (HV)[_v] = *(const f16x8*)(_hp + _v * 8); \
    }                                                                        \
  } while (0)

  LD_ROW(e0, lA, hA);
  LD_ROW(e0 + 1, lB, hB);

  for (int i = e0; i < e1; i += 2) {
    {
      float v = lA + aldn;
      f16x8 t[NV];
#pragma unroll
      for (int vv = 0; vv < NV; ++vv) t[vv] = hA[vv];
      LD_ROW(i + 2, lA, hA);
      v = v > 0.f ? v : NEG_SLOPE * v;
      float xv = __expf(v);
      den += xv;
#pragma unroll
      for (int vv = 0; vv < NV; ++vv)
#pragma unroll
        for (int j = 0; j < 8; ++j) acc[vv * 8 + j] += xv * (float)t[vv][j];
    }
    if (i + 1 < e1) {
      float v = lB + aldn;
      f16x8 t[NV];
#pragma unroll
      for (int vv = 0; vv < NV; ++vv) t[vv] = hB[vv];
      LD_ROW(i + 3, lB, hB);
      v = v > 0.f ? v : NEG_SLOPE * v;
      float xv = __expf(v);
      den += xv;
#pragma unroll
      for (int vv = 0; vv < NV; ++vv)
#pragma unroll
        for (int j = 0; j < 8; ++j) acc[vv * 8 + j] += xv * (float)t[vv][j];
    }
  }
#undef LD_ROW

  float invd = 1.f / den;
#pragma unroll
  for (int v = 0; v < NV; ++v) {
    f16x8 o;
#pragma unroll
    for (int j = 0; j < 8; ++j) {
      float r = acc[v * 8 + j] * invd + bias[c0 + v * 8 + j];
      o[j] = (_Float16)(r > 0.f ? r : 0.f);
    }
    __builtin_nontemporal_store(o, (f16x8*)&oh[(size_t)n * HC + c0 + v * 8]);
  }
}

// last layer: H=1, C=64, tanh output (f32); 4 nodes per block (wave per node)
__global__ __launch_bounds__(256) void k_agg_last(
    const _Float16* __restrict__ h, const float* __restrict__ als,
    const float* __restrict__ ald, const int* __restrict__ rptr,
    const int* __restrict__ csrc, const float* __restrict__ bias,
    float* __restrict__ of) {
  int wave = threadIdx.x >> 6, t = threadIdx.x & 63;
  int n = blockIdx.x * 4 + wave;
  float acc = 0.f, den = 0.f;
  float aldn = ald[n];
  int e0 = rptr[n], e1 = rptr[n + 1];
  for (int i = e0; i < e1; ++i) {
    int s = csrc[i];
    float v = als[s] + aldn;
    v = v > 0.f ? v : NEG_SLOPE * v;
    float xv = __expf(v);
    den += xv;
    acc += xv * (float)h[(size_t)s * 64 + t];
  }
  of[(size_t)n * 64 + t] = tanhf(acc / den + bias[t]);
}

// ---------------- host side -------------------------------------------------
static inline size_t alup(size_t x) { return (x + 255) & ~(size_t)255; }

struct Scratch {
  _Float16* xb; _Float16* wtb1; _Float16* wtb2; _Float16* wtb3; _Float16* h;
  float* zb;   // als1,ald1,als2,ald2,als3,ald3 contiguous (NN*18 floats)
  int* cnt; int* rptr; int* cursor; int* csrc;
};

static void run_layer(hipStream_t stream, const Scratch& S, const _Float16* xin,
                      const _Float16* wtb, float* als, float* ald,
                      int K, int N, int H, int C,
                      const float* as_, const float* ad_, const float* bias,
                      int mode, _Float16* oh, float* of) {
  int gx = (N + 127) / 128, gy = (NN + 127) / 128;
  k_gemm<<<gx * gy, 256, 0, stream>>>(xin, wtb, S.h, as_, ad_, als, ald,
                                      NN, N, K, gx, H, C);
  if (mode == 0) {
    if (C == 256)      k_aggw<4, 256, 0><<<NN / 4, 256, 0, stream>>>(S.h, als, ald, S.rptr, S.csrc, bias, oh, of);
    else if (C == 128) k_aggw<4, 128, 0><<<NN / 4, 256, 0, stream>>>(S.h, als, ald, S.rptr, S.csrc, bias, oh, of);
  } else {
    k_agg_last<<<NN / 4, 256, 0, stream>>>(S.h, als, ald, S.rptr, S.csrc, bias, of);
  }
}

extern "C" void kernel_launch(void* const* d_in, const int* in_sizes, int n_in,
                              void* d_out, int out_size, void* d_ws, size_t ws_size,
                              hipStream_t stream) {
  const float* x   = (const float*)d_in[0];
  const int*   ei  = (const int*)d_in[1];
  const float* W1  = (const float*)d_in[2];
  const float* a1s = (const float*)d_in[3];
  const float* a1d = (const float*)d_in[4];
  const float* b1  = (const float*)d_in[5];
  const float* W2  = (const float*)d_in[6];
  const float* a2s = (const float*)d_in[7];
  const float* a2d = (const float*)d_in[8];
  const float* b2  = (const float*)d_in[9];
  const float* W3  = (const float*)d_in[10];
  const float* a3s = (const float*)d_in[11];
  const float* a3d = (const float*)d_in[12];
  const float* b3  = (const float*)d_in[13];
  float* out = (float*)d_out;

  char* p = (char*)d_ws;
  Scratch S;
  S.xb   = (_Float16*)p; p += alup((size_t)NN * 1024 * 2);
  S.wtb1 = (_Float16*)p; p += alup((size_t)1024 * 768 * 2);
  S.wtb2 = (_Float16*)p; p += alup((size_t)512 * 1024 * 2);
  S.wtb3 = (_Float16*)p; p += alup((size_t)64 * 512 * 2);
  S.h    = (_Float16*)p; p += alup((size_t)NN * 1024 * 2);
  S.zb   = (float*)p;    p += alup((size_t)NN * 18 * 4);
  S.cnt  = (int*)p;      p += alup((size_t)NN * 4);
  S.rptr = (int*)p;      p += alup((size_t)(NN + 1) * 4);
  S.cursor=(int*)p;      p += alup((size_t)NN * 4);
  S.csrc = (int*)p;      p += alup((size_t)ET * 4);

  float* als1 = S.zb;
  float* ald1 = als1 + NN * 4;
  float* als2 = ald1 + NN * 4;
  float* ald2 = als2 + NN * 4;
  float* als3 = ald2 + NN * 4;
  float* ald3 = als3 + NN;

  // fused init: 3 weight transposes + cnt=0 + als/ald=0 + x->f16
  k_init<<<1312 + 1024, 256, 0, stream>>>(x, S.xb, S.cnt, S.zb, NN * 18,
                                          W1, S.wtb1, W2, S.wtb2, W3, S.wtb3);
  // CSR build (per-launch, deterministic work)
  k_count<<<(ET + 255) / 256, 256, 0, stream>>>(ei, S.cnt);
  k_scan<<<1, 1024, 0, stream>>>(S.cnt, S.rptr, S.cursor);
  k_fill<<<(ET + 255) / 256, 256, 0, stream>>>(ei, S.cursor, S.csrc);

  // layer 1: K=768, H=4, C=256, relu -> f16
  run_layer(stream, S, S.xb, S.wtb1, als1, ald1, 768, 1024, 4, 256, a1s, a1d, b1, 0, S.xb, nullptr);
  // layer 2: K=1024, H=4, C=128, relu -> f16
  run_layer(stream, S, S.xb, S.wtb2, als2, ald2, 1024, 512, 4, 128, a2s, a2d, b2, 0, S.xb, nullptr);
  // layer 3: K=512, H=1, C=64, tanh -> f32 out
  run_layer(stream, S, S.xb, S.wtb3, als3, ald3, 512, 64, 1, 64, a3s, a3d, b3, 1, nullptr, out);
}